// Round 1
// baseline (126.850 us; speedup 1.0000x reference)
//
#include <hip/hip_runtime.h>
#include <math.h>

#define NPTS   1024
#define CH1    32
#define CH2    64
#define NDIAG  10
#define TK     16
#define KMAX   64
#define R2     0.0225f

// One block per query point. 256 threads = 4 waves.
// Exploits: 24 rotation diagonals collapse to 10 signed-axis diags (+8x a
// constant term); ball-group + topk + max collapses to "max over all in-ball
// neighbors" (self = zero vector is always present, fallback slots are zero).
__global__ __launch_bounds__(256) void point_encoder_kernel(
    const float* __restrict__ xg,
    const float* __restrict__ W1g,
    const float* __restrict__ b1g,
    const float* __restrict__ W2g,
    const float* __restrict__ b2g,
    float* __restrict__ outg)
{
    __shared__ float xs[NPTS * 3];              // 12 KB: this batch's points
    __shared__ float nb[KMAX * 3];              // in-ball relative coords
    __shared__ float h1s[TK * NDIAG * CH1];     // 20 KB: h1 tile
    __shared__ unsigned int maccU[CH2 * NDIAG]; // per-(o,i) max (post-relu)
    __shared__ float W1s[CH1 * 3];
    __shared__ float b1s[CH1];
    __shared__ int cnt;

    const int tid  = threadIdx.x;
    const int bid  = blockIdx.x;
    const int b    = bid >> 10;            // NPTS = 1024
    const int n    = bid & (NPTS - 1);
    const int wave = tid >> 6;
    const int o    = tid & 63;             // output channel for this lane

    // ---- stage ----
    const float* xb = xg + b * NPTS * 3;
    for (int i = tid; i < NPTS * 3; i += 256) xs[i] = xb[i];
    if (tid < CH1 * 3) W1s[tid] = W1g[tid];
    if (tid < CH1)     b1s[tid] = b1g[tid];
    for (int i = tid; i < CH2 * NDIAG; i += 256) maccU[i] = 0u;
    if (tid == 0) cnt = 0;

    // per-lane W2 row + b2 in registers (tiny, L1-cached global reads)
    float w2r[CH1];
    const float4* W2v = (const float4*)W2g;
    #pragma unroll
    for (int j = 0; j < 8; ++j) {
        float4 v = W2v[o * 8 + j];
        w2r[4*j+0] = v.x; w2r[4*j+1] = v.y; w2r[4*j+2] = v.z; w2r[4*j+3] = v.w;
    }
    const float b2o = b2g[o];

    __syncthreads();

    // ---- in-ball neighbor scan (includes self: d2 = 0) ----
    const float qx = xs[n*3+0], qy = xs[n*3+1], qz = xs[n*3+2];
    for (int p = tid; p < NPTS; p += 256) {
        float dx = xs[p*3+0] - qx;
        float dy = xs[p*3+1] - qy;
        float dz = xs[p*3+2] - qz;
        float d2 = dx*dx + dy*dy + dz*dz;
        if (d2 <= R2) {
            int s = atomicAdd(&cnt, 1);
            if (s < KMAX) { nb[s*3+0] = dx; nb[s*3+1] = dy; nb[s*3+2] = dz; }
        }
    }
    __syncthreads();

    int cn = cnt; if (cn > KMAX) cn = KMAX;   // >64 in-ball is a >13-sigma event
    const int ntiles = (cn + TK - 1) / TK;
    const int padded = ntiles * TK;
    // pad with zero vectors: zero vector is already in the set (self), so
    // padding cannot change the max
    for (int p = cn + tid; p < padded; p += 256) {
        nb[p*3+0] = 0.f; nb[p*3+1] = 0.f; nb[p*3+2] = 0.f;
    }

    float mx[NDIAG];
    #pragma unroll
    for (int i = 0; i < NDIAG; ++i) mx[i] = -INFINITY;

    for (int t = 0; t < ntiles; ++t) {
        __syncthreads();
        // ---- h1 tile: (k in [0,16)) x (10 diags) x (c in [0,32)) ----
        // diag entries are 0/+-1 -> multiplies fold into adds
        #pragma unroll
        for (int rep = 0; rep < 2; ++rep) {
            int p = tid + rep * 256;           // p in [0, 512): (k, c)
            int k = p >> 5;
            int c = p & 31;
            float gx = nb[(t*TK + k)*3 + 0];
            float gy = nb[(t*TK + k)*3 + 1];
            float gz = nb[(t*TK + k)*3 + 2];
            float tx = W1s[c*3+0] * gx;
            float ty = W1s[c*3+1] * gy;
            float tz = W1s[c*3+2] * gz;
            float bb = b1s[c];
            float* hp = &h1s[k * (NDIAG*CH1) + c];
            hp[0*CH1] = fmaxf(bb + tx + ty + tz, 0.f);  // ( 1, 1, 1)
            hp[1*CH1] = fmaxf(bb + tx - ty - tz, 0.f);  // ( 1,-1,-1)
            hp[2*CH1] = fmaxf(bb - tx + ty - tz, 0.f);  // (-1, 1,-1)
            hp[3*CH1] = fmaxf(bb - tx - ty + tz, 0.f);  // (-1,-1, 1)
            hp[4*CH1] = fmaxf(bb + tx, 0.f);            // ( 1, 0, 0)
            hp[5*CH1] = fmaxf(bb - tx, 0.f);            // (-1, 0, 0)
            hp[6*CH1] = fmaxf(bb + ty, 0.f);            // ( 0, 1, 0)
            hp[7*CH1] = fmaxf(bb - ty, 0.f);            // ( 0,-1, 0)
            hp[8*CH1] = fmaxf(bb + tz, 0.f);            // ( 0, 0, 1)
            hp[9*CH1] = fmaxf(bb - tz, 0.f);            // ( 0, 0,-1)
        }
        __syncthreads();
        // ---- h2 dot: lane = channel o; wave w covers k = 4w..4w+3 ----
        // h1 rows read as wave-uniform float4 -> LDS broadcast, conflict-free
        #pragma unroll
        for (int u = 0; u < 4; ++u) {
            const int k = wave * 4 + u;
            #pragma unroll
            for (int i = 0; i < NDIAG; ++i) {
                const float4* hp = (const float4*)&h1s[(k*NDIAG + i) * CH1];
                float s = b2o;
                #pragma unroll
                for (int j = 0; j < 8; ++j) {
                    float4 h = hp[j];
                    s += w2r[4*j+0]*h.x + w2r[4*j+1]*h.y
                       + w2r[4*j+2]*h.z + w2r[4*j+3]*h.w;
                }
                mx[i] = fmaxf(mx[i], s);
            }
        }
    }

    // relu(max) == max(relu); nonneg IEEE floats order like uints -> atomicMax
    #pragma unroll
    for (int i = 0; i < NDIAG; ++i) {
        unsigned int v = __float_as_uint(fmaxf(mx[i], 0.f));
        atomicMax(&maccU[o * NDIAG + i], v);
    }
    __syncthreads();

    if (tid < CH2) {
        // zero-diag constant term (8 of the 24 rotations): relu(W2 relu(b1)+b2)
        float s = b2o;
        #pragma unroll
        for (int c = 0; c < CH1; ++c) s += w2r[c] * fmaxf(b1s[c], 0.f);
        float f = 8.f * fmaxf(s, 0.f);
        const float WGT[NDIAG] = {1.f,1.f,1.f,1.f,2.f,2.f,2.f,2.f,2.f,2.f};
        #pragma unroll
        for (int i = 0; i < NDIAG; ++i)
            f += WGT[i] * __uint_as_float(maccU[o * NDIAG + i]);
        outg[b * (CH2 * NPTS) + o * NPTS + n] = f * (1.f / 24.f);
    }
}

extern "C" void kernel_launch(void* const* d_in, const int* in_sizes, int n_in,
                              void* d_out, int out_size, void* d_ws, size_t ws_size,
                              hipStream_t stream) {
    const float* x  = (const float*)d_in[0];
    const float* W1 = (const float*)d_in[1];
    const float* b1 = (const float*)d_in[2];
    const float* W2 = (const float*)d_in[3];
    const float* b2 = (const float*)d_in[4];
    float* out = (float*)d_out;

    const int total = in_sizes[0] / 3;   // B * N = 2048 query points
    point_encoder_kernel<<<total, 256, 0, stream>>>(x, W1, b1, W2, b2, out);
}

// Round 2
// 103.540 us; speedup vs baseline: 1.2251x; 1.2251x over previous
//
#include <hip/hip_runtime.h>
#include <math.h>

#define NPTS   1024
#define CH1    32
#define CH2    64
#define NDIAG  10
#define TK     8
#define KMAX   64
#define R2     0.0225f

// One block per query point, 256 threads = 4 waves.
// R1 -> R2 changes:
//  * 2 output channels per lane (o = lane&31 and +32): per h1-row LDS read we
//    now do 64 FMAs, halving the ds_read_b128 count in the LDS-bound h2 stage.
//  * dropped the 12 KB xs staging (x is L1/L2 resident; scan reads global) and
//    shrank the h1 tile to TK=8 -> LDS ~14.5 KB -> more resident blocks.
__global__ __launch_bounds__(256, 4) void point_encoder_kernel(
    const float* __restrict__ xg,
    const float* __restrict__ W1g,
    const float* __restrict__ b1g,
    const float* __restrict__ W2g,
    const float* __restrict__ b2g,
    float* __restrict__ outg)
{
    __shared__ float nb[KMAX * 3];              // in-ball relative coords
    __shared__ float h1s[TK * NDIAG * CH1];     // 10 KB h1 tile
    __shared__ unsigned int maccU[CH2 * NDIAG]; // per-(o,i) running max
    __shared__ float W1s[CH1 * 3];
    __shared__ float b1s[CH1];
    __shared__ int cnt;

    const int tid  = threadIdx.x;
    const int bid  = blockIdx.x;
    const int b    = bid >> 10;            // NPTS = 1024
    const int n    = bid & (NPTS - 1);
    const int wave = tid >> 6;
    const int half = (tid >> 5) & 1;
    const int oc   = tid & 31;             // this lane: channels oc and oc+32

    // ---- init ----
    if (tid < CH1 * 3) W1s[tid] = W1g[tid];
    if (tid < CH1)     b1s[tid] = b1g[tid];
    for (int i = tid; i < CH2 * NDIAG; i += 256) maccU[i] = 0u;
    if (tid == 0) cnt = 0;

    // two W2 rows per lane, in registers (64 VGPRs)
    float w2a[CH1], w2b[CH1];
    const float4* W2v = (const float4*)W2g;
    #pragma unroll
    for (int j = 0; j < 8; ++j) {
        float4 va = W2v[oc * 8 + j];
        float4 vb = W2v[(oc + 32) * 8 + j];
        w2a[4*j+0] = va.x; w2a[4*j+1] = va.y; w2a[4*j+2] = va.z; w2a[4*j+3] = va.w;
        w2b[4*j+0] = vb.x; w2b[4*j+1] = vb.y; w2b[4*j+2] = vb.z; w2b[4*j+3] = vb.w;
    }
    const float b2a = b2g[oc], b2b = b2g[oc + 32];

    __syncthreads();   // cnt=0 visible before scan atomics

    // ---- in-ball neighbor scan (self included, d2 = 0) ----
    const float* xb = xg + b * NPTS * 3;
    const float qx = xb[n*3+0], qy = xb[n*3+1], qz = xb[n*3+2];
    for (int p = tid; p < NPTS; p += 256) {
        float dx = xb[p*3+0] - qx;
        float dy = xb[p*3+1] - qy;
        float dz = xb[p*3+2] - qz;
        float d2 = dx*dx + dy*dy + dz*dz;
        if (d2 <= R2) {
            int s = atomicAdd(&cnt, 1);
            if (s < KMAX) { nb[s*3+0] = dx; nb[s*3+1] = dy; nb[s*3+2] = dz; }
        }
    }
    __syncthreads();

    int cn = cnt; if (cn > KMAX) cn = KMAX;
    const int ntiles = (cn + TK - 1) / TK;
    const int padded = ntiles * TK;
    // zero-vector padding never changes the max (self = zero is in the set)
    for (int p = cn + tid; p < padded; p += 256) {
        nb[p*3+0] = 0.f; nb[p*3+1] = 0.f; nb[p*3+2] = 0.f;
    }

    float mx0[NDIAG], mx1[NDIAG];
    #pragma unroll
    for (int i = 0; i < NDIAG; ++i) { mx0[i] = -INFINITY; mx1[i] = -INFINITY; }

    const int klocal = wave * 2 + half;    // this half-wave's k within the tile

    for (int t = 0; t < ntiles; ++t) {
        __syncthreads();   // pad/nb ready; previous h2 done with h1s
        // ---- h1 tile build: exactly 256 work items (8 k x 32 c) ----
        {
            int k = tid >> 5;
            int c = tid & 31;
            float gx = nb[(t*TK + k)*3 + 0];
            float gy = nb[(t*TK + k)*3 + 1];
            float gz = nb[(t*TK + k)*3 + 2];
            float tx = W1s[c*3+0] * gx;
            float ty = W1s[c*3+1] * gy;
            float tz = W1s[c*3+2] * gz;
            float bb = b1s[c];
            float* hp = &h1s[k * (NDIAG*CH1) + c];
            hp[0*CH1] = fmaxf(bb + tx + ty + tz, 0.f);  // ( 1, 1, 1)
            hp[1*CH1] = fmaxf(bb + tx - ty - tz, 0.f);  // ( 1,-1,-1)
            hp[2*CH1] = fmaxf(bb - tx + ty - tz, 0.f);  // (-1, 1,-1)
            hp[3*CH1] = fmaxf(bb - tx - ty + tz, 0.f);  // (-1,-1, 1)
            hp[4*CH1] = fmaxf(bb + tx, 0.f);            // ( 1, 0, 0)
            hp[5*CH1] = fmaxf(bb - tx, 0.f);            // (-1, 0, 0)
            hp[6*CH1] = fmaxf(bb + ty, 0.f);            // ( 0, 1, 0)
            hp[7*CH1] = fmaxf(bb - ty, 0.f);            // ( 0,-1, 0)
            hp[8*CH1] = fmaxf(bb + tz, 0.f);            // ( 0, 0, 1)
            hp[9*CH1] = fmaxf(bb - tz, 0.f);            // ( 0, 0,-1)
        }
        __syncthreads();
        // ---- h2: each half-wave owns one k; each lane two o channels ----
        // 8 x ds_read_b128 per column now feeds 64 FMAs (2 o rows).
        // Half-wave addresses differ by 1280 B = same banks -> 2-way = free.
        #pragma unroll
        for (int i = 0; i < NDIAG; ++i) {
            const float4* hp = (const float4*)&h1s[(klocal*NDIAG + i) * CH1];
            float s0 = b2a, s1 = b2b;
            #pragma unroll
            for (int j = 0; j < 8; ++j) {
                float4 h = hp[j];
                s0 += w2a[4*j+0]*h.x + w2a[4*j+1]*h.y
                    + w2a[4*j+2]*h.z + w2a[4*j+3]*h.w;
                s1 += w2b[4*j+0]*h.x + w2b[4*j+1]*h.y
                    + w2b[4*j+2]*h.z + w2b[4*j+3]*h.w;
            }
            mx0[i] = fmaxf(mx0[i], s0);
            mx1[i] = fmaxf(mx1[i], s1);
        }
    }

    // relu(max) == max(relu); nonneg IEEE floats order like uints
    #pragma unroll
    for (int i = 0; i < NDIAG; ++i) {
        atomicMax(&maccU[oc * NDIAG + i],        __float_as_uint(fmaxf(mx0[i], 0.f)));
        atomicMax(&maccU[(oc+32) * NDIAG + i],   __float_as_uint(fmaxf(mx1[i], 0.f)));
    }
    __syncthreads();

    if (tid < CH2) {
        // zero-diag constant (8 of 24 rotations): relu(W2 relu(b1) + b2)
        float s = b2g[tid];
        const float* w2row = W2g + tid * CH1;
        #pragma unroll
        for (int c = 0; c < CH1; ++c) s += w2row[c] * fmaxf(b1s[c], 0.f);
        float f = 8.f * fmaxf(s, 0.f);
        const float WGT[NDIAG] = {1.f,1.f,1.f,1.f,2.f,2.f,2.f,2.f,2.f,2.f};
        #pragma unroll
        for (int i = 0; i < NDIAG; ++i)
            f += WGT[i] * __uint_as_float(maccU[tid * NDIAG + i]);
        outg[b * (CH2 * NPTS) + tid * NPTS + n] = f * (1.f / 24.f);
    }
}

extern "C" void kernel_launch(void* const* d_in, const int* in_sizes, int n_in,
                              void* d_out, int out_size, void* d_ws, size_t ws_size,
                              hipStream_t stream) {
    const float* x  = (const float*)d_in[0];
    const float* W1 = (const float*)d_in[1];
    const float* b1 = (const float*)d_in[2];
    const float* W2 = (const float*)d_in[3];
    const float* b2 = (const float*)d_in[4];
    float* out = (float*)d_out;

    const int total = in_sizes[0] / 3;   // B * N = 2048 query points
    point_encoder_kernel<<<total, 256, 0, stream>>>(x, W1, b1, W2, b2, out);
}

// Round 3
// 80.914 us; speedup vs baseline: 1.5677x; 1.2796x over previous
//
#include <hip/hip_runtime.h>
#include <math.h>

typedef _Float16 half8 __attribute__((ext_vector_type(8)));
typedef float    f32x4 __attribute__((ext_vector_type(4)));

#define NPTS 1024
#define KMAX 64
#define R2   0.0225f

// One WAVE per query point; block = 4 waves = 4 consecutive points.
// h2 via MFMA 16x16x32 f16: M = k-slot (16 neighbors/tile), N = o (4 tiles of
// 16), K = c (32, one K-step). A-fragment (h1) is built directly in registers
// from the lane's 8 W1 rows -- no LDS, no barriers in the hot path.
// "max over k" = in-lane max over the 4 C rows + 2 cross-quad shuffles.
// 24 rotation diagonals collapse to 10 signed-axis diags + 8x const term
// (treated as an 11th diag with weight 8, g = 0).
__global__ __launch_bounds__(256, 2) void point_encoder_kernel(
    const float* __restrict__ xg,
    const float* __restrict__ W1g,
    const float* __restrict__ b1g,
    const float* __restrict__ W2g,
    const float* __restrict__ b2g,
    float* __restrict__ outg)
{
    __shared__ float nbs[4][KMAX * 3];   // per-wave neighbor rel-coords
    __shared__ float ost[4][64];         // output staging for coalesced write

    const int tid  = threadIdx.x;
    const int wid  = tid >> 6;
    const int lane = tid & 63;
    const int kl   = lane & 15;          // A: m = k-slot ; B/C: n = o_local
    const int quad = lane >> 4;          // K-dim group: c = quad*8 + j

    const int p = blockIdx.x * 4 + wid;  // global point id
    const int b = p >> 10;
    const int n = p & (NPTS - 1);

    // ---- per-lane constants: W1 rows + b1 for c = quad*8+j ----
    float w1x[8], w1y[8], w1z[8], b1r[8];
    #pragma unroll
    for (int j = 0; j < 8; ++j) {
        const int c = quad * 8 + j;
        w1x[j] = W1g[c*3+0];
        w1y[j] = W1g[c*3+1];
        w1z[j] = W1g[c*3+2];
        b1r[j] = b1g[c];
    }
    // B fragments: W2^T per o-tile.  B[k=c][n=o]: lane holds W2[o][quad*8+j].
    half8 Bf[4];
    float b2v[4];
    #pragma unroll
    for (int nt = 0; nt < 4; ++nt) {
        const int o = nt * 16 + kl;
        #pragma unroll
        for (int j = 0; j < 8; ++j)
            Bf[nt][j] = (_Float16)W2g[o * 32 + quad * 8 + j];
        b2v[nt] = b2g[o];
    }

    // ---- wave-local in-ball scan with ballot compaction ----
    float* nb = nbs[wid];
    nb[lane] = 0.f; nb[lane + 64] = 0.f; nb[lane + 128] = 0.f;  // zero-pad
    const float* xb = xg + b * NPTS * 3;
    const float qx = xb[n*3+0], qy = xb[n*3+1], qz = xb[n*3+2];
    int base = 0;
    for (int it = 0; it < 16; ++it) {
        const int idx = it * 64 + lane;
        const float dx = xb[idx*3+0] - qx;
        const float dy = xb[idx*3+1] - qy;
        const float dz = xb[idx*3+2] - qz;
        const float d2 = dx*dx + dy*dy + dz*dz;
        const bool pred = (d2 <= R2);
        const unsigned long long mask = __ballot(pred);
        const int pos = base + __popcll(mask & ((1ull << lane) - 1ull));
        if (pred && pos < KMAX) {
            nb[pos*3+0] = dx; nb[pos*3+1] = dy; nb[pos*3+2] = dz;
        }
        base += __popcll(mask);
    }
    int cn = base < KMAX ? base : KMAX;      // self (d2=0) always present
    const int ntiles = (cn + 15) >> 4;       // 1..4, wave-uniform
    // zero-padded slots give h1 = relu(b1) = the self-point value -> padding
    // can never change the max.

    // ---- per-(diag, o-tile) partial max (over this lane's 4 C rows) ----
    float mv[11][4];
    #pragma unroll
    for (int i = 0; i < 11; ++i)
        #pragma unroll
        for (int nt = 0; nt < 4; ++nt) mv[i][nt] = -INFINITY;

    for (int mt = 0; mt < ntiles; ++mt) {
        const int k = mt * 16 + kl;
        const float gx = nb[k*3+0], gy = nb[k*3+1], gz = nb[k*3+2];
        half8 A[11];
        #pragma unroll
        for (int j = 0; j < 8; ++j) {
            const float tx = w1x[j] * gx;
            const float ty = w1y[j] * gy;
            const float tz = w1z[j] * gz;
            const float pxy = tx + ty, mxy = tx - ty;
            const float bpz = b1r[j] + tz, bmz = b1r[j] - tz;
            A[0][j] = (_Float16)fmaxf(bpz + pxy, 0.f);   // ( 1, 1, 1)
            A[1][j] = (_Float16)fmaxf(bmz + mxy, 0.f);   // ( 1,-1,-1)
            A[2][j] = (_Float16)fmaxf(bmz - mxy, 0.f);   // (-1, 1,-1)
            A[3][j] = (_Float16)fmaxf(bpz - pxy, 0.f);   // (-1,-1, 1)
            A[4][j] = (_Float16)fmaxf(b1r[j] + tx, 0.f); // ( 1, 0, 0)
            A[5][j] = (_Float16)fmaxf(b1r[j] - tx, 0.f); // (-1, 0, 0)
            A[6][j] = (_Float16)fmaxf(b1r[j] + ty, 0.f); // ( 0, 1, 0)
            A[7][j] = (_Float16)fmaxf(b1r[j] - ty, 0.f); // ( 0,-1, 0)
            A[8][j] = (_Float16)fmaxf(bpz, 0.f);         // ( 0, 0, 1)
            A[9][j] = (_Float16)fmaxf(bmz, 0.f);         // ( 0, 0,-1)
            A[10][j] = (_Float16)fmaxf(b1r[j], 0.f);     // zero diag (const)
        }
        #pragma unroll
        for (int i = 0; i < 11; ++i) {
            if (i == 10 && mt != 0) continue;  // const diag: one tile suffices
            #pragma unroll
            for (int nt = 0; nt < 4; ++nt) {
                f32x4 C = {0.f, 0.f, 0.f, 0.f};
                C = __builtin_amdgcn_mfma_f32_16x16x32_f16(A[i], Bf[nt], C, 0, 0, 0);
                const float r = fmaxf(fmaxf(C[0], C[1]), fmaxf(C[2], C[3]));
                mv[i][nt] = fmaxf(mv[i][nt], r);
            }
        }
    }

    // ---- cross-quad max, bias, relu, weighted sum over diags ----
    float acc[4] = {0.f, 0.f, 0.f, 0.f};
    #pragma unroll
    for (int i = 0; i < 11; ++i) {
        const float wgt = (i < 4) ? 1.f : (i < 10) ? 2.f : 8.f;
        #pragma unroll
        for (int nt = 0; nt < 4; ++nt) {
            float r = mv[i][nt];
            r = fmaxf(r, __shfl_xor(r, 16));
            r = fmaxf(r, __shfl_xor(r, 32));
            acc[nt] += wgt * fmaxf(r + b2v[nt], 0.f);
        }
    }

    // lane holds acc[nt] for o = nt*16 + (lane&15); o = lane -> acc[quad]
    const float f = (quad == 0 ? acc[0] : quad == 1 ? acc[1]
                   : quad == 2 ? acc[2] : acc[3]) * (1.f / 24.f);
    ost[wid][lane] = f;
    __syncthreads();
    if (tid < 64) {
        float4 v = make_float4(ost[0][tid], ost[1][tid], ost[2][tid], ost[3][tid]);
        const int n0 = (blockIdx.x * 4) & (NPTS - 1);
        const int bb = (blockIdx.x * 4) >> 10;
        *(float4*)(outg + (size_t)(bb * 64 + tid) * NPTS + n0) = v;
    }
}

extern "C" void kernel_launch(void* const* d_in, const int* in_sizes, int n_in,
                              void* d_out, int out_size, void* d_ws, size_t ws_size,
                              hipStream_t stream) {
    const float* x  = (const float*)d_in[0];
    const float* W1 = (const float*)d_in[1];
    const float* b1 = (const float*)d_in[2];
    const float* W2 = (const float*)d_in[3];
    const float* b2 = (const float*)d_in[4];
    float* out = (float*)d_out;

    const int total  = in_sizes[0] / 3;        // B*N = 2048 points
    const int blocks = (total + 3) / 4;        // 4 points (waves) per block
    point_encoder_kernel<<<blocks, 256, 0, stream>>>(x, W1, b1, W2, b2, out);
}

// Round 4
// 75.719 us; speedup vs baseline: 1.6753x; 1.0686x over previous
//
#include <hip/hip_runtime.h>
#include <math.h>

typedef _Float16 half8 __attribute__((ext_vector_type(8)));
typedef float    f32x4 __attribute__((ext_vector_type(4)));

#define NPTS 1024
#define KMAX 64
#define R2   0.0225f

// Block = ONE query point, 4 waves. The 10 signed-axis diagonals are split
// across waves {3,3,2,2}; wave 3 also computes the zero-diag const term (x8)
// via one extra MFMA set. Scan over the 1024 support points is split 4 ways
// (256 points per wave, ballot compaction into a shared LDS list). Weights
// are staged once per block into LDS (W2 pre-converted to f16 so each wave's
// B-fragment is a single ds_read_b128 per o-tile).
// MFMA 16x16x32 f16: M = k-slot, N = o (4 tiles of 16), K = c (one step).
__global__ __launch_bounds__(256, 4) void point_encoder_kernel(
    const float* __restrict__ xg,
    const float* __restrict__ W1g,
    const float* __restrict__ b1g,
    const float* __restrict__ W2g,
    const float* __restrict__ b2g,
    float* __restrict__ outg)
{
    __shared__ __align__(16) float    w1b[32 * 4];   // {W1x,W1y,W1z,b1} per c
    __shared__ __align__(16) _Float16 W2h[64 * 32];  // f16 W2, row-major [o][c]
    __shared__ float b2s[64];
    __shared__ float nb[KMAX * 3];                   // in-ball rel coords
    __shared__ float ost[4][64];                     // per-wave partial sums
    __shared__ int   cnt;

    const int tid  = threadIdx.x;
    const int wid  = tid >> 6;
    const int lane = tid & 63;
    const int kl   = lane & 15;     // A: m = k-slot ; B/C: n = o_local
    const int quad = lane >> 4;     // K-group: c = quad*8 + j

    const int b = blockIdx.x >> 10;           // NPTS = 1024
    const int n = blockIdx.x & (NPTS - 1);

    // ---- block-level staging (coalesced) ----
    if (tid < 32) {
        w1b[tid*4+0] = W1g[tid*3+0];
        w1b[tid*4+1] = W1g[tid*3+1];
        w1b[tid*4+2] = W1g[tid*3+2];
        w1b[tid*4+3] = b1g[tid];
    }
    #pragma unroll
    for (int i = 0; i < 8; ++i) W2h[i*256 + tid] = (_Float16)W2g[i*256 + tid];
    if (tid < 64)       b2s[tid] = b2g[tid];
    if (tid < KMAX * 3) nb[tid]  = 0.f;   // zero-pad: never changes the max
    if (tid == 0)       cnt = 0;
    __syncthreads();

    // ---- per-lane fragments from LDS ----
    f32x4 w1r[8];                    // {x,y,z,b1} for c = quad*8+j
    #pragma unroll
    for (int j = 0; j < 8; ++j)
        w1r[j] = *(const f32x4*)&w1b[(quad*8 + j) * 4];
    half8 Bf[4];                     // B[k=c][n=o]: lane holds W2[o][quad*8+j]
    float b2v[4];
    #pragma unroll
    for (int nt = 0; nt < 4; ++nt) {
        Bf[nt]  = *(const half8*)&W2h[(nt*16 + kl) * 32 + quad * 8];
        b2v[nt] = b2s[nt*16 + kl];
    }

    // ---- in-ball scan: wave w covers points [w*256, w*256+256) ----
    const float* xb = xg + b * NPTS * 3;
    const float qx = xb[n*3+0], qy = xb[n*3+1], qz = xb[n*3+2];
    #pragma unroll
    for (int it = 0; it < 4; ++it) {
        const int idx = wid * 256 + it * 64 + lane;
        const float dx = xb[idx*3+0] - qx;
        const float dy = xb[idx*3+1] - qy;
        const float dz = xb[idx*3+2] - qz;
        const float d2 = dx*dx + dy*dy + dz*dz;
        const bool pred = (d2 <= R2);
        const unsigned long long mask = __ballot(pred);
        const int cit = __popcll(mask);
        int base0 = 0;
        if (lane == 0 && cit) base0 = atomicAdd(&cnt, cit);
        base0 = __shfl(base0, 0, 64);
        const int pos = base0 + __popcll(mask & ((1ull << lane) - 1ull));
        if (pred && pos < KMAX) {
            nb[pos*3+0] = dx; nb[pos*3+1] = dy; nb[pos*3+2] = dz;
        }
    }
    __syncthreads();
    int cn = cnt; if (cn > KMAX) cn = KMAX;   // self (d2=0) always present
    const int ntiles = (cn + 15) >> 4;        // 1..4, typically 1

    // ---- const diag (8 of 24 rotations), wave 3 only: A = relu(b1) ----
    float mvc[4] = {0.f, 0.f, 0.f, 0.f};
    if (wid == 3) {
        half8 Ac;
        #pragma unroll
        for (int j = 0; j < 8; ++j) Ac[j] = (_Float16)fmaxf(w1r[j].w, 0.f);
        #pragma unroll
        for (int nt = 0; nt < 4; ++nt) {
            f32x4 C = {0.f, 0.f, 0.f, 0.f};
            C = __builtin_amdgcn_mfma_f32_16x16x32_f16(Ac, Bf[nt], C, 0, 0, 0);
            mvc[nt] = fmaxf(fmaxf(C[0], C[1]), fmaxf(C[2], C[3]));
        }
    }

    // ---- this wave's diag subset over the neighbor tiles ----
    const int nd = (wid < 2) ? 3 : 2;
    float mv[3][4];
    #pragma unroll
    for (int d = 0; d < 3; ++d)
        #pragma unroll
        for (int nt = 0; nt < 4; ++nt) mv[d][nt] = -INFINITY;

    for (int mt = 0; mt < ntiles; ++mt) {
        const int k = mt * 16 + kl;
        const float gx = nb[k*3+0], gy = nb[k*3+1], gz = nb[k*3+2];
        half8 A[3];
        #pragma unroll
        for (int j = 0; j < 8; ++j) {
            const float tx = w1r[j].x * gx;
            const float ty = w1r[j].y * gy;
            const float tz = w1r[j].z * gz;
            const float bb = w1r[j].w;
            float a0, a1, a2 = 0.f;
            if (wid == 0)      { a0 = bb+tx+ty+tz; a1 = bb+tx-ty-tz; a2 = bb-tx+ty-tz; }
            else if (wid == 1) { a0 = bb-tx-ty+tz; a1 = bb+tx;       a2 = bb-tx;       }
            else if (wid == 2) { a0 = bb+ty;       a1 = bb-ty;                          }
            else               { a0 = bb+tz;       a1 = bb-tz;                          }
            A[0][j] = (_Float16)fmaxf(a0, 0.f);
            A[1][j] = (_Float16)fmaxf(a1, 0.f);
            A[2][j] = (_Float16)fmaxf(a2, 0.f);
        }
        #pragma unroll
        for (int d = 0; d < 3; ++d) {
            if (d >= nd) break;            // wave-uniform
            #pragma unroll
            for (int nt = 0; nt < 4; ++nt) {
                f32x4 C = {0.f, 0.f, 0.f, 0.f};
                C = __builtin_amdgcn_mfma_f32_16x16x32_f16(A[d], Bf[nt], C, 0, 0, 0);
                const float r = fmaxf(fmaxf(C[0], C[1]), fmaxf(C[2], C[3]));
                mv[d][nt] = fmaxf(mv[d][nt], r);
            }
        }
    }

    // ---- per-wave epilogue: cross-quad max, bias, relu, weighted sum ----
    float accv[4] = {0.f, 0.f, 0.f, 0.f};
    #pragma unroll
    for (int d = 0; d < 3; ++d) {
        if (d >= nd) break;
        // diag weights: w0 {1,1,1}; w1 {1,2,2}; w2 {2,2}; w3 {2,2}
        const float wgt = (wid == 0 || (wid == 1 && d == 0)) ? 1.f : 2.f;
        #pragma unroll
        for (int nt = 0; nt < 4; ++nt) {
            float r = mv[d][nt];
            r = fmaxf(r, __shfl_xor(r, 16, 64));
            r = fmaxf(r, __shfl_xor(r, 32, 64));
            accv[nt] += wgt * fmaxf(r + b2v[nt], 0.f);
        }
    }
    if (wid == 3) {
        #pragma unroll
        for (int nt = 0; nt < 4; ++nt)
            accv[nt] += 8.f * fmaxf(mvc[nt] + b2v[nt], 0.f);  // const diag x8
    }

    // lane holds accv[nt] for o = nt*16 + kl; pick o = lane -> accv[quad]
    ost[wid][lane] = (quad == 0) ? accv[0] : (quad == 1) ? accv[1]
                   : (quad == 2) ? accv[2] : accv[3];
    __syncthreads();
    if (tid < 64) {
        const float s = (ost[0][tid] + ost[1][tid] + ost[2][tid] + ost[3][tid])
                        * (1.f / 24.f);
        outg[(size_t)b * (64 * NPTS) + (size_t)tid * NPTS + n] = s;
    }
}

extern "C" void kernel_launch(void* const* d_in, const int* in_sizes, int n_in,
                              void* d_out, int out_size, void* d_ws, size_t ws_size,
                              hipStream_t stream) {
    const float* x  = (const float*)d_in[0];
    const float* W1 = (const float*)d_in[1];
    const float* b1 = (const float*)d_in[2];
    const float* W2 = (const float*)d_in[3];
    const float* b2 = (const float*)d_in[4];
    float* out = (float*)d_out;

    const int total = in_sizes[0] / 3;   // B*N = 2048 points = blocks
    point_encoder_kernel<<<total, 256, 0, stream>>>(x, W1, b1, W2, b2, out);
}

// Round 5
// 75.260 us; speedup vs baseline: 1.6855x; 1.0061x over previous
//
#include <hip/hip_runtime.h>
#include <math.h>

typedef _Float16 half8 __attribute__((ext_vector_type(8)));
typedef float    f32x4 __attribute__((ext_vector_type(4)));

#define NPTS 1024
#define KMAX 64
#define R2   0.0225f

// Block = ONE query point, 4 fully independent waves.
// Wave nt owns output tile o in [nt*16, nt*16+16) COMPLETELY: it computes all
// 10 signed-axis diagonals (+ the zero-diag const term, weight 8) against its
// own B-fragment -- so there is no cross-wave partial-sum combine, no final
// barrier, and each wave stores its 16 outputs directly.
// Weights are loaded straight into registers (coalesced float4s) at the top
// and first consumed AFTER the scan barrier -> their load latency hides under
// the neighbor scan. LDS holds only the shared neighbor list (+cnt).
// MFMA 16x16x32 f16: M = k-slot, N = o_local, K = c (one K-step).
__global__ __launch_bounds__(256, 4) void point_encoder_kernel(
    const float* __restrict__ xg,
    const float* __restrict__ W1g,
    const float* __restrict__ b1g,
    const float* __restrict__ W2g,
    const float* __restrict__ b2g,
    float* __restrict__ outg)
{
    __shared__ float nb[KMAX * 3];   // compacted in-ball rel coords (shared)
    __shared__ int   cnt;

    const int tid  = threadIdx.x;
    const int nt   = tid >> 6;       // wave id == o-tile id
    const int lane = tid & 63;
    const int kl   = lane & 15;      // A: m = k-slot ; B/C: n = o_local
    const int quad = lane >> 4;      // K-group: c = quad*8 + j

    const int b = blockIdx.x >> 10;  // NPTS = 1024
    const int n = blockIdx.x & (NPTS - 1);

    // ---- issue all weight loads up front (consumed only after the scan) ----
    const int o = nt * 16 + kl;
    const f32x4 w2a = *(const f32x4*)(W2g + o * 32 + quad * 8);
    const f32x4 w2b = *(const f32x4*)(W2g + o * 32 + quad * 8 + 4);
    const float b2v = b2g[o];
    f32x4 w1raw[6];                  // W1 rows quad*8 .. quad*8+7 (stride 3)
    #pragma unroll
    for (int j = 0; j < 6; ++j)
        w1raw[j] = *(const f32x4*)(W1g + quad * 24 + j * 4);
    const f32x4 b1a = *(const f32x4*)(b1g + quad * 8);
    const f32x4 b1b = *(const f32x4*)(b1g + quad * 8 + 4);

    if (tid < KMAX * 3) nb[tid] = 0.f;   // zero-pad: h1=relu(b1)=self value,
    if (tid == 0)       cnt = 0;         // can never change the max
    __syncthreads();

    // ---- in-ball scan: wave nt covers support points [nt*256, nt*256+256) ----
    const float* xb = xg + b * NPTS * 3;
    const float qx = xb[n*3+0], qy = xb[n*3+1], qz = xb[n*3+2];
    #pragma unroll
    for (int it = 0; it < 4; ++it) {
        const int idx = nt * 256 + it * 64 + lane;
        const float dx = xb[idx*3+0] - qx;
        const float dy = xb[idx*3+1] - qy;
        const float dz = xb[idx*3+2] - qz;
        const float d2 = dx*dx + dy*dy + dz*dz;
        const bool pred = (d2 <= R2);
        const unsigned long long mask = __ballot(pred);
        const int cit = __popcll(mask);
        int base0 = 0;
        if (lane == 0 && cit) base0 = atomicAdd(&cnt, cit);
        base0 = __shfl(base0, 0, 64);
        const int pos = base0 + __popcll(mask & ((1ull << lane) - 1ull));
        if (pred && pos < KMAX) {
            nb[pos*3+0] = dx; nb[pos*3+1] = dy; nb[pos*3+2] = dz;
        }
    }
    __syncthreads();
    int cn = cnt; if (cn > KMAX) cn = KMAX;   // self (d2=0) always present
    const int ntiles = (cn + 15) >> 4;        // 1..4, typically 1-2

    // ---- unpack register-resident weights into fragments ----
    half8 Bf;                        // B[k=c][n=o]: lane holds W2[o][quad*8+j]
    #pragma unroll
    for (int j = 0; j < 4; ++j) {
        Bf[j]     = (_Float16)w2a[j];
        Bf[j + 4] = (_Float16)w2b[j];
    }
    float w1x[8], w1y[8], w1z[8], b1r[8];
    #pragma unroll
    for (int j = 0; j < 8; ++j) {
        w1x[j] = w1raw[(j*3    ) >> 2][(j*3    ) & 3];
        w1y[j] = w1raw[(j*3 + 1) >> 2][(j*3 + 1) & 3];
        w1z[j] = w1raw[(j*3 + 2) >> 2][(j*3 + 2) & 3];
        b1r[j] = (j < 4) ? b1a[j] : b1b[j - 4];
    }

    // ---- zero-diag const term (8 of 24 rotations): A = relu(b1) ----
    // all A rows identical -> all C rows identical -> no reduce needed
    half8 Ac;
    #pragma unroll
    for (int j = 0; j < 8; ++j) Ac[j] = (_Float16)fmaxf(b1r[j], 0.f);
    f32x4 Cc = {0.f, 0.f, 0.f, 0.f};
    Cc = __builtin_amdgcn_mfma_f32_16x16x32_f16(Ac, Bf, Cc, 0, 0, 0);
    float acc = 8.f * fmaxf(Cc[0] + b2v, 0.f);

    // ---- neighbor tiles: all 10 diags x this wave's o-tile ----
    float mv[10];
    #pragma unroll
    for (int i = 0; i < 10; ++i) mv[i] = -INFINITY;

    for (int mt = 0; mt < ntiles; ++mt) {
        const int k = mt * 16 + kl;
        const float gx = nb[k*3+0], gy = nb[k*3+1], gz = nb[k*3+2];
        half8 A[10];
        #pragma unroll
        for (int j = 0; j < 8; ++j) {
            const float tx = w1x[j] * gx;
            const float ty = w1y[j] * gy;
            const float tz = w1z[j] * gz;
            const float pxy = tx + ty, mxy = tx - ty;
            const float bpz = b1r[j] + tz, bmz = b1r[j] - tz;
            A[0][j] = (_Float16)fmaxf(bpz + pxy, 0.f);   // ( 1, 1, 1)
            A[1][j] = (_Float16)fmaxf(bmz + mxy, 0.f);   // ( 1,-1,-1)
            A[2][j] = (_Float16)fmaxf(bmz - mxy, 0.f);   // (-1, 1,-1)
            A[3][j] = (_Float16)fmaxf(bpz - pxy, 0.f);   // (-1,-1, 1)
            A[4][j] = (_Float16)fmaxf(b1r[j] + tx, 0.f); // ( 1, 0, 0)
            A[5][j] = (_Float16)fmaxf(b1r[j] - tx, 0.f); // (-1, 0, 0)
            A[6][j] = (_Float16)fmaxf(b1r[j] + ty, 0.f); // ( 0, 1, 0)
            A[7][j] = (_Float16)fmaxf(b1r[j] - ty, 0.f); // ( 0,-1, 0)
            A[8][j] = (_Float16)fmaxf(bpz, 0.f);         // ( 0, 0, 1)
            A[9][j] = (_Float16)fmaxf(bmz, 0.f);         // ( 0, 0,-1)
        }
        #pragma unroll
        for (int i = 0; i < 10; ++i) {
            f32x4 C = {0.f, 0.f, 0.f, 0.f};
            C = __builtin_amdgcn_mfma_f32_16x16x32_f16(A[i], Bf, C, 0, 0, 0);
            mv[i] = fmaxf(mv[i], fmaxf(fmaxf(C[0], C[1]), fmaxf(C[2], C[3])));
        }
    }

    // ---- cross-quad max, bias, relu, weighted sum; direct store ----
    #pragma unroll
    for (int i = 0; i < 10; ++i) {
        float r = mv[i];
        r = fmaxf(r, __shfl_xor(r, 16, 64));
        r = fmaxf(r, __shfl_xor(r, 32, 64));
        acc += ((i < 4) ? 1.f : 2.f) * fmaxf(r + b2v, 0.f);
    }
    if (quad == 0)
        outg[(size_t)b * (64 * NPTS) + (size_t)o * NPTS + n] = acc * (1.f / 24.f);
}

extern "C" void kernel_launch(void* const* d_in, const int* in_sizes, int n_in,
                              void* d_out, int out_size, void* d_ws, size_t ws_size,
                              hipStream_t stream) {
    const float* x  = (const float*)d_in[0];
    const float* W1 = (const float*)d_in[1];
    const float* b1 = (const float*)d_in[2];
    const float* W2 = (const float*)d_in[3];
    const float* b2 = (const float*)d_in[4];
    float* out = (float*)d_out;

    const int total = in_sizes[0] / 3;   // B*N = 2048 points = blocks
    point_encoder_kernel<<<total, 256, 0, stream>>>(x, W1, b1, W2, b2, out);
}